// Round 1
// baseline (10018.246 us; speedup 1.0000x reference)
//
#include <hip/hip_runtime.h>
#include <cstdint>
#include <cstddef>

#define NROWS 16
#define NTHR  256
#define HSZ   256
#define ESZ   64
#define VSZ   26
#define NCOMP 15
#define BATCH 65536

// If samples come back wholesale-wrong, flip to 0 (pre-0.4.30 JAX threefry counters).
#define JAX_PARTITIONABLE 1

// ---------------- threefry2x32 (exact JAX semantics) ----------------
__device__ __forceinline__ uint32_t rotl32(uint32_t v, int d) {
  return (v << d) | (v >> (32 - d));
}

__device__ __forceinline__ void tf2x32(uint32_t kA, uint32_t kB,
                                       uint32_t& x0, uint32_t& x1) {
  uint32_t kC = kA ^ kB ^ 0x1BD11BDAu;
  x0 += kA; x1 += kB;
#define TFR(r) { x0 += x1; x1 = rotl32(x1, r); x1 ^= x0; }
  TFR(13) TFR(15) TFR(26) TFR(6)
  x0 += kB; x1 += kC + 1u;
  TFR(17) TFR(29) TFR(16) TFR(24)
  x0 += kC; x1 += kA + 2u;
  TFR(13) TFR(15) TFR(26) TFR(6)
  x0 += kA; x1 += kB + 3u;
  TFR(17) TFR(29) TFR(16) TFR(24)
  x0 += kB; x1 += kC + 4u;
  TFR(13) TFR(15) TFR(26) TFR(6)
  x0 += kC; x1 += kA + 5u;
#undef TFR
}

// ---------------- XLA-matching transcendentals ----------------
// XLA elemental tanh: Eigen rational approximation, emitted as plain mul/add
// (no FMA contraction), clamp to +-7.90531110763549805, |x|<0.0004 -> x.
__device__ __forceinline__ float xla_tanh(float x) {
  #pragma clang fp contract(off)
  float ax = fabsf(x);
  float xc = fminf(fmaxf(x, -7.90531110763549805f), 7.90531110763549805f);
  float x2 = xc * xc;
  float nu = -2.76076847742355e-16f;
  nu = x2 * nu + 2.00018790482477e-13f;
  nu = x2 * nu + -8.60467152213735e-11f;
  nu = x2 * nu + 5.12229709037114e-08f;
  nu = x2 * nu + 1.48572235717979e-05f;
  nu = x2 * nu + 6.37261928875436e-04f;
  nu = x2 * nu + 4.89352455891786e-03f;
  nu = xc * nu;
  float de = 1.19825839466702e-06f;
  de = x2 * de + 1.18534705686654e-04f;
  de = x2 * de + 2.26843463243900e-03f;
  de = x2 * de + 4.89352518554385e-03f;
  float r = nu / de;
  return (ax < 0.0004f) ? x : r;
}

// XLA LogisticExpander: logistic(x) = 0.5 + 0.5*tanh(0.5*x)
__device__ __forceinline__ float xla_sigmoid(float x) {
  #pragma clang fp contract(off)
  return 0.5f + 0.5f * xla_tanh(0.5f * x);
}

// Eigen/Cephes plog (XLA CPU vectorized log). Input: positive normal float.
__device__ __forceinline__ float xla_log(float x) {
  #pragma clang fp contract(off)
  uint32_t bits = __float_as_uint(x);
  int ei = (int)(bits >> 23) - 126;
  float m = __uint_as_float((bits & 0x007FFFFFu) | 0x3F000000u);  // [0.5,1)
  bool lt = m < 0.707106781186547524f;
  float ee = (float)ei - (lt ? 1.0f : 0.0f);
  float mm = (m - 1.0f) + (lt ? m : 0.0f);
  float x2 = mm * mm;
  float x3 = x2 * mm;
  float y  = __builtin_fmaf(7.0376836292E-2f,  mm, -1.1514610310E-1f);
  float y1 = __builtin_fmaf(-1.2420140846E-1f, mm,  1.4249322787E-1f);
  float y2 = __builtin_fmaf(2.0000714765E-1f,  mm, -2.4999993993E-1f);
  y  = __builtin_fmaf(y,  mm, 1.1676998740E-1f);
  y1 = __builtin_fmaf(y1, mm, -1.6668057665E-1f);
  y2 = __builtin_fmaf(y2, mm, 3.3333331174E-1f);
  y  = __builtin_fmaf(y, x3, y1);
  y  = __builtin_fmaf(y, x3, y2);
  y  = y * x3;
  float t1 = ee * -2.12194440e-4f;
  float t2 = 0.5f * x2;
  y  = y + t1;
  mm = mm - t2;
  float t3 = ee * 0.693359375f;
  mm = mm + y;
  mm = mm + t3;
  return mm;
}

// ---------------- sequential-k FMA chain: 4 gate columns x 16 rows ----------------
// W layout: W[k*1024 + col], cols owned by this thread: u, 256+u, 512+u, 768+u.
// lds layout: lds[k*16 + r].
__device__ __forceinline__ void chain4(float* aI, float* aF, float* aG, float* aO,
                                       const float* lds, const float* W, int u, int nk) {
  const float* w = W + u;
  for (int k = 0; k < nk; ++k) {
    float wI = w[0], wF = w[256], wG = w[512], wO = w[768];
    w += 1024;
    float hv[16];
    *(float4*)&hv[0]  = *(const float4*)(lds + k * 16 + 0);
    *(float4*)&hv[4]  = *(const float4*)(lds + k * 16 + 4);
    *(float4*)&hv[8]  = *(const float4*)(lds + k * 16 + 8);
    *(float4*)&hv[12] = *(const float4*)(lds + k * 16 + 12);
    #pragma unroll
    for (int r = 0; r < 16; ++r) {
      aI[r] = __builtin_fmaf(hv[r], wI, aI[r]);
      aF[r] = __builtin_fmaf(hv[r], wF, aF[r]);
      aG[r] = __builtin_fmaf(hv[r], wG, aG[r]);
      aO[r] = __builtin_fmaf(hv[r], wO, aO[r]);
    }
  }
}

__global__ __launch_bounds__(NTHR, 2) void belief_main(
    const float* __restrict__ ctx, const float* __restrict__ embed,
    const float* __restrict__ start_e, const float* __restrict__ Wp,
    const float* __restrict__ bp, const float* __restrict__ Wi,
    const float* __restrict__ Wh, const float* __restrict__ bh,
    const float* __restrict__ Wo, const float* __restrict__ bo,
    const int* __restrict__ seedp, float* __restrict__ out,
    float* __restrict__ ctxG, int fast) {
  __shared__ __align__(16) float hT[HSZ * NROWS];      // h transposed [k][r]
  __shared__ __align__(16) float ctxT[HSZ * NROWS];    // ctx transposed [m][r]
  __shared__ __align__(16) float prevT[ESZ * NROWS];   // prev embed [e][r]
  __shared__ __align__(16) float woLds[HSZ * VSZ];
  __shared__ float boLds[VSZ];
  __shared__ float scores[NROWS * VSZ];
  __shared__ int tokLds[NROWS];
  __shared__ uint32_t skLds[NCOMP * 2];

  const int t = threadIdx.x;
  const int b0 = blockIdx.x * NROWS;

  // ---- stage LDS ----
  #pragma unroll
  for (int r = 0; r < NROWS; ++r)
    ctxT[t * NROWS + r] = ctx[(size_t)(b0 + r) * HSZ + t];
  for (int i = t; i < HSZ * VSZ; i += NTHR) woLds[i] = Wo[i];
  if (t < VSZ) boLds[t] = bo[t];
  for (int i = t; i < ESZ * NROWS; i += NTHR) prevT[i] = start_e[i >> 4];
  if (t < NCOMP) {
    // jax.random.split (fold-like / partitionable): subkey[t] = tf(key, 0, t)
    uint32_t x0, x1;
#if JAX_PARTITIONABLE
    x0 = 0u; x1 = (uint32_t)t;
    tf2x32(0u, (uint32_t)seedp[0], x0, x1);
    skLds[2 * t] = x0; skLds[2 * t + 1] = x1;
#else
    // original split: counts=iota(30); out = concat(r0,r1); sk[t]=(out[2t],out[2t+1])
    {
      uint32_t idx0 = (uint32_t)(2 * t), idx1 = (uint32_t)(2 * t + 1);
      // out[j] for j<15 is r0 of pair (j, j+15); for j>=15 it's r1 of pair (j-15, j)
      uint32_t a, b;
      if (idx0 < 15u) { a = idx0; b = idx0 + 15u; tf2x32(0u, (uint32_t)seedp[0], a, b); skLds[2*t] = a; }
      else            { a = idx0 - 15u; b = idx0; tf2x32(0u, (uint32_t)seedp[0], a, b); skLds[2*t] = b; }
      if (idx1 < 15u) { a = idx1; b = idx1 + 15u; tf2x32(0u, (uint32_t)seedp[0], a, b); skLds[2*t+1] = a; }
      else            { a = idx1 - 15u; b = idx1; tf2x32(0u, (uint32_t)seedp[0], a, b); skLds[2*t+1] = b; }
    }
#endif
  }
  __syncthreads();

  // ---- h0 = tanh(ctx @ Wp + bp), thread t owns hidden unit t, rows 0..15 ----
  float c[NROWS];
  {
    float acc[NROWS];
    #pragma unroll
    for (int r = 0; r < NROWS; ++r) acc[r] = 0.0f;
    const float* wp = Wp + t;
    for (int m = 0; m < HSZ; ++m) {
      float w = wp[(size_t)m * HSZ];
      float hv[16];
      *(float4*)&hv[0]  = *(const float4*)&ctxT[m * NROWS + 0];
      *(float4*)&hv[4]  = *(const float4*)&ctxT[m * NROWS + 4];
      *(float4*)&hv[8]  = *(const float4*)&ctxT[m * NROWS + 8];
      *(float4*)&hv[12] = *(const float4*)&ctxT[m * NROWS + 12];
      #pragma unroll
      for (int r = 0; r < NROWS; ++r) acc[r] = __builtin_fmaf(hv[r], w, acc[r]);
    }
    float bpv = bp[t];
    #pragma unroll
    for (int r = 0; r < NROWS; ++r) {
      float s = acc[r] + bpv;          // plain add (no contraction possible)
      hT[t * NROWS + r] = xla_tanh(s);
      c[r] = 0.0f;
    }
  }

  // ---- ctx @ Wi[0:256] prefix, precomputed once if workspace is big enough ----
  if (fast) {
    float aI[16], aF[16], aG[16], aO[16];
    #pragma unroll
    for (int r = 0; r < 16; ++r) { aI[r] = 0.f; aF[r] = 0.f; aG[r] = 0.f; aO[r] = 0.f; }
    chain4(aI, aF, aG, aO, ctxT, Wi, t, HSZ);
    #pragma unroll
    for (int r = 0; r < 16; ++r) {
      size_t base = (size_t)(b0 + r) * 1024 + t;
      ctxG[base] = aI[r]; ctxG[base + 256] = aF[r];
      ctxG[base + 512] = aG[r]; ctxG[base + 768] = aO[r];
    }
  }
  __syncthreads();

  const float bhI = bh[t], bhF = bh[256 + t], bhG = bh[512 + t], bhO = bh[768 + t];
  const float* WiP = Wi + (size_t)HSZ * 1024;  // prev-embed rows of Wi

  for (int s = 0; s < NCOMP; ++s) {
    // dotA = x @ Wi  (sequential k: ctx rows 0..255, then prev rows 256..319)
    float aI[16], aF[16], aG[16], aO[16];
    if (fast) {
      #pragma unroll
      for (int r = 0; r < 16; ++r) {
        size_t base = (size_t)(b0 + r) * 1024 + t;
        aI[r] = ctxG[base]; aF[r] = ctxG[base + 256];
        aG[r] = ctxG[base + 512]; aO[r] = ctxG[base + 768];
      }
    } else {
      #pragma unroll
      for (int r = 0; r < 16; ++r) { aI[r] = 0.f; aF[r] = 0.f; aG[r] = 0.f; aO[r] = 0.f; }
      chain4(aI, aF, aG, aO, ctxT, Wi, t, HSZ);
    }
    chain4(aI, aF, aG, aO, prevT, WiP, t, ESZ);

    // dotB = h @ Wh (separate accumulator; added afterwards like XLA)
    float bI[16], bF[16], bG[16], bO[16];
    #pragma unroll
    for (int r = 0; r < 16; ++r) { bI[r] = 0.f; bF[r] = 0.f; bG[r] = 0.f; bO[r] = 0.f; }
    chain4(bI, bF, bG, bO, hT, Wh, t, HSZ);

    // pointwise LSTM cell (plain mul/add, XLA-style no contraction)
    float hnew[16];
    {
      #pragma clang fp contract(off)
      #pragma unroll
      for (int r = 0; r < 16; ++r) {
        float gi = (aI[r] + bI[r]) + bhI;
        float gf = (aF[r] + bF[r]) + bhF;
        float gg = (aG[r] + bG[r]) + bhG;
        float go = (aO[r] + bO[r]) + bhO;
        float si = xla_sigmoid(gi);
        float sf = xla_sigmoid(gf);
        float tg = xla_tanh(gg);
        float so = xla_sigmoid(go);
        float cn = sf * c[r] + si * tg;
        c[r] = cn;
        hnew[r] = so * xla_tanh(cn);
      }
    }
    __syncthreads();                       // all waves done reading hT/prevT
    #pragma unroll
    for (int r = 0; r < 16; ++r) hT[t * NROWS + r] = hnew[r];
    __syncthreads();

    // logits + gumbel + scores
    uint32_t sk0 = skLds[2 * s], sk1 = skLds[2 * s + 1];
    for (int p = t; p < NROWS * VSZ; p += NTHR) {
      int r = p / VSZ, v = p - r * VSZ;
      float acc = 0.0f;
      for (int k = 0; k < HSZ; ++k)
        acc = __builtin_fmaf(hT[k * NROWS + r], woLds[k * VSZ + v], acc);
      float logit = acc + boLds[v];
      out[(size_t)(b0 + r) * (NCOMP * VSZ) + s * VSZ + v] = logit;

      // random bits for element (b, v) of the (B, V) gumbel draw
      uint32_t n = (uint32_t)(b0 + r) * VSZ + (uint32_t)v;
      uint32_t x0, x1, rb;
#if JAX_PARTITIONABLE
      x0 = 0u; x1 = n;
      tf2x32(sk0, sk1, x0, x1);
      rb = x0 ^ x1;
#else
      {
        const uint32_t half = (uint32_t)(BATCH * VSZ / 2);
        if (n < half) { x0 = n; x1 = n + half; tf2x32(sk0, sk1, x0, x1); rb = x0; }
        else          { x0 = n - half; x1 = n; tf2x32(sk0, sk1, x0, x1); rb = x1; }
      }
#endif
      float f = __uint_as_float((rb >> 9) | 0x3F800000u) - 1.0f;
      float uu;
      {
        #pragma clang fp contract(off)
        uu = f + 1.17549435082228751e-38f;           // floats*(1-tiny)+tiny == f+tiny
      }
      uu = fmaxf(1.17549435082228751e-38f, uu);
      float l1 = xla_log(uu);
      float g = -xla_log(-l1);
      {
        #pragma clang fp contract(off)
        scores[r * VSZ + v] = g + logit;
      }
    }
    __syncthreads();

    // argmax (first max index), write sample, pick next embedding
    if (t < NROWS) {
      float mbest = scores[t * VSZ];
      int ibest = 0;
      for (int v = 1; v < VSZ; ++v) {
        float sc = scores[t * VSZ + v];
        if (sc > mbest) { mbest = sc; ibest = v; }
      }
      tokLds[t] = ibest;
      out[(size_t)BATCH * (NCOMP * VSZ) + (size_t)(b0 + t) * NCOMP + s] = (float)ibest;
    }
    __syncthreads();
    if (s < NCOMP - 1) {
      for (int i = t; i < ESZ * NROWS; i += NTHR) {
        int e = i >> 4, r = i & 15;
        prevT[i] = embed[tokLds[r] * ESZ + e];
      }
    }
    __syncthreads();
  }
}

extern "C" void kernel_launch(void* const* d_in, const int* in_sizes, int n_in,
                              void* d_out, int out_size, void* d_ws, size_t ws_size,
                              hipStream_t stream) {
  const float* ctx     = (const float*)d_in[0];
  const float* embed   = (const float*)d_in[1];
  const float* start_e = (const float*)d_in[2];
  const float* Wp      = (const float*)d_in[3];
  const float* bp      = (const float*)d_in[4];
  const float* Wi      = (const float*)d_in[5];
  const float* Wh      = (const float*)d_in[6];
  const float* bh      = (const float*)d_in[7];
  const float* Wo      = (const float*)d_in[8];
  const float* bo      = (const float*)d_in[9];
  const int*   seedp   = (const int*)d_in[10];
  float* out = (float*)d_out;

  size_t need = (size_t)BATCH * 1024 * sizeof(float);  // 268 MB ctx-gates prefix
  int fast = (d_ws != nullptr && ws_size >= need) ? 1 : 0;
  float* ctxG = (float*)d_ws;

  hipLaunchKernelGGL(belief_main, dim3(BATCH / NROWS), dim3(NTHR), 0, stream,
                     ctx, embed, start_e, Wp, bp, Wi, Wh, bh, Wo, bo, seedp,
                     out, ctxG, fast);
}